// Round 2
// baseline (1330.611 us; speedup 1.0000x reference)
//
#include <hip/hip_runtime.h>
#include <hip/hip_bf16.h>

#define HH 160
#define WW 160
#define HW 25600
#define NC 256
#define NB 8

typedef short short8 __attribute__((ext_vector_type(8)));
typedef float f32x4 __attribute__((ext_vector_type(4)));

__device__ __forceinline__ unsigned short f2bf(float f) {
    unsigned u = __float_as_uint(f);
    u += 0x7fffu + ((u >> 16) & 1u);   // RNE
    return (unsigned short)(u >> 16);
}
__device__ __forceinline__ float bf2f(unsigned short h) {
    return __uint_as_float(((unsigned)h) << 16);
}

// ---------------- K0: fold BN into align 1x1 conv, split hi/lo bf16, pre-pack ----------------
// Writes the padded per-kk LDS image directly: wpkh[kk*10240 + co*40 + kq] (kq = k - 32*kk).
// Pad shorts 32..39 per row are never read downstream.
__global__ void k0_fold(const float* __restrict__ aw, const float* __restrict__ ag,
                        const float* __restrict__ ab, const float* __restrict__ am,
                        const float* __restrict__ av,
                        unsigned short* __restrict__ wpkh, unsigned short* __restrict__ wpkl,
                        float* __restrict__ biasp) {
    int co = blockIdx.x, t = threadIdx.x;       // t = k (ci)
    float sc = ag[co] * rsqrtf(av[co] + 1e-5f);
    float w = aw[co * 256 + t] * sc;
    unsigned short h = f2bf(w);
    int kk = t >> 5, kq = t & 31;
    wpkh[kk * 10240 + co * 40 + kq] = h;
    wpkl[kk * 10240 + co * 40 + kq] = f2bf(w - bf2f(h));
    if (t == 0) biasp[co] = ab[co] - am[co] * sc;
}

// ---------------- K0b: fold the 49-way mean of conv2 into effective weights ----------------
__global__ void k0b_fold2(const float* __restrict__ ow2, const float* __restrict__ ob2,
                          float* __restrict__ weff, float* __restrict__ beff) {
    int t = threadIdx.x;
    if (t < 288) {
        int g = t / 144, r = t - g * 144;
        float s = 0.f;
        for (int q = 0; q < 49; q++) s += ow2[(size_t)(g * 49 + q) * 144 + r];
        weff[t] = s * (1.f / 49.f);
    }
    if (t < 2) {
        float s = 0.f;
        for (int q = 0; q < 49; q++) s += ob2[t * 49 + q];
        beff[t] = s * (1.f / 49.f);
    }
}

// ---------------- K1: align GEMM (split-bf16 MFMA, ~fp32) + bias + SiLU ----------------
// BM=256 (4 waves x 64 co), BN=128, BK=32. A staged via global_load_lds from the
// pre-packed padded image; B converted in-register (RNE hi/lo, bit-identical to prior).
__global__ __launch_bounds__(256, 2) void k1_gemm(
    const float* __restrict__ X, const unsigned short* __restrict__ Wph,
    const unsigned short* __restrict__ Wpl,
    const float* __restrict__ biasp, float* __restrict__ xal) {
    __shared__ __align__(16) unsigned short Ah[10240];   // [co][kq] stride 40 (80 B rows)
    __shared__ __align__(16) unsigned short Al[10240];
    __shared__ __align__(16) unsigned short Bh[5120];    // [n][kq] stride 40, n 0..127
    __shared__ __align__(16) unsigned short Bl[5120];

    int t = threadIdx.x;
    int n0 = blockIdx.x * 128;
    int b  = blockIdx.y;
    const float* Xb = X + (size_t)b * NC * HW;

    int lane = t & 63, wv = t >> 6;
    int lcol = lane & 15, lq = lane >> 4;

    f32x4 acc[4][8];
#pragma unroll
    for (int i = 0; i < 4; i++)
#pragma unroll
        for (int j = 0; j < 8; j++) { f32x4 z = {0.f, 0.f, 0.f, 0.f}; acc[i][j] = z; }

    int bn2 = t & 63;       // pixel-pair index (pixels 2*bn2, 2*bn2+1)
    int bkq = t >> 6;       // base k-quad (== wv)

    for (int kk = 0; kk < 8; kk++) {
        // ---- A: async global->LDS, 20 KB hi + 20 KB lo, linear image copy ----
        const char* gah = (const char*)(Wph + kk * 10240);
        const char* gal = (const char*)(Wpl + kk * 10240);
#pragma unroll
        for (int i = 0; i < 5; i++) {
            int off = wv * 1024 + i * 4096;    // wave-uniform byte offset
            __builtin_amdgcn_global_load_lds(
                (const __attribute__((address_space(1))) unsigned int*)(gah + off + lane * 16),
                (__attribute__((address_space(3))) unsigned int*)((char*)Ah + off),
                16, 0, 0);
            __builtin_amdgcn_global_load_lds(
                (const __attribute__((address_space(1))) unsigned int*)(gal + off + lane * 16),
                (__attribute__((address_space(3))) unsigned int*)((char*)Al + off),
                16, 0, 0);
        }
        // ---- B: load fp32, RNE hi/lo split, stage to LDS ----
#pragma unroll
        for (int j2 = 0; j2 < 2; j2++) {
            int kq = bkq + 4 * j2;             // k-quad 0..7
            const float* src = Xb + (size_t)(kk * 32 + kq * 4) * HW + n0 + bn2 * 2;
            unsigned h0[2], h1[2], l0[2], l1[2];
#pragma unroll
            for (int j = 0; j < 2; j++) {
                float2 v0 = *(const float2*)(src + (size_t)(2 * j) * HW);
                float2 v1 = *(const float2*)(src + (size_t)(2 * j + 1) * HW);
                unsigned short a = f2bf(v0.x), bq = f2bf(v1.x);
                unsigned short c = f2bf(v0.y), d = f2bf(v1.y);
                h0[j] = (unsigned)a | ((unsigned)bq << 16);
                h1[j] = (unsigned)c | ((unsigned)d << 16);
                unsigned short la = f2bf(v0.x - bf2f(a)), lb = f2bf(v1.x - bf2f(bq));
                unsigned short lc = f2bf(v0.y - bf2f(c)), ld = f2bf(v1.y - bf2f(d));
                l0[j] = (unsigned)la | ((unsigned)lb << 16);
                l1[j] = (unsigned)lc | ((unsigned)ld << 16);
            }
            *(uint2*)(&Bh[(bn2 * 2) * 40 + kq * 4])     = make_uint2(h0[0], h0[1]);
            *(uint2*)(&Bh[(bn2 * 2 + 1) * 40 + kq * 4]) = make_uint2(h1[0], h1[1]);
            *(uint2*)(&Bl[(bn2 * 2) * 40 + kq * 4])     = make_uint2(l0[0], l0[1]);
            *(uint2*)(&Bl[(bn2 * 2 + 1) * 40 + kq * 4]) = make_uint2(l1[0], l1[1]);
        }
        __syncthreads();   // drains global_load_lds (vmcnt) + ds_writes

        short8 afh[4], afl[4];
#pragma unroll
        for (int mt = 0; mt < 4; mt++) {
            afh[mt] = *(const short8*)(&Ah[(wv * 64 + mt * 16 + lcol) * 40 + lq * 8]);
            afl[mt] = *(const short8*)(&Al[(wv * 64 + mt * 16 + lcol) * 40 + lq * 8]);
        }
#pragma unroll 2
        for (int nt = 0; nt < 8; nt++) {
            short8 bh = *(const short8*)(&Bh[(nt * 16 + lcol) * 40 + lq * 8]);
            short8 bl = *(const short8*)(&Bl[(nt * 16 + lcol) * 40 + lq * 8]);
#pragma unroll
            for (int mt = 0; mt < 4; mt++) {
                acc[mt][nt] = __builtin_amdgcn_mfma_f32_16x16x32_bf16(
                    afh[mt], bh, acc[mt][nt], 0, 0, 0);
                acc[mt][nt] = __builtin_amdgcn_mfma_f32_16x16x32_bf16(
                    afh[mt], bl, acc[mt][nt], 0, 0, 0);
                acc[mt][nt] = __builtin_amdgcn_mfma_f32_16x16x32_bf16(
                    afl[mt], bh, acc[mt][nt], 0, 0, 0);
            }
        }
        __syncthreads();
    }
#pragma unroll
    for (int mt = 0; mt < 4; mt++) {
#pragma unroll
        for (int r = 0; r < 4; r++) {
            int co = wv * 64 + mt * 16 + lq * 4 + r;
            float bias = biasp[co];
            size_t rowbase = ((size_t)b * NC + co) * HW + n0;
#pragma unroll
            for (int nt = 0; nt < 8; nt++) {
                int n = nt * 16 + lcol;
                float y = acc[mt][nt][r] + bias;
                float z = y / (1.f + __expf(-y));   // SiLU
                xal[rowbase + n] = z;
            }
        }
    }
}

// ---------------- KA: per-(b,c) stats: 16 cell sums + cell maxes ----------------
__global__ void ka_stats(const float* __restrict__ xal,
                         float* __restrict__ cellsum, float* __restrict__ cellmax) {
    __shared__ float redS[256], redM[256];
    int bc = blockIdx.x;
    int t = threadIdx.x;
    int cell = t >> 4, s = t & 15;
    int ch = cell >> 2, cw = cell & 3;
    const float* base = xal + (size_t)bc * HW;
    float sm = 0.f, mx = -3.4e38f;
    for (int k = 0; k < 100; k++) {
        int idx = s + 16 * k;            // 0..1599 within cell
        int r = idx / 40, col = idx - r * 40;
        float v = base[(ch * 40 + r) * 160 + cw * 40 + col];
        sm += v;
        mx = fmaxf(mx, v);
    }
    redS[t] = sm;
    redM[t] = mx;
    __syncthreads();
    if (s == 0) {
        float cs = 0.f, cm = -3.4e38f;
#pragma unroll
        for (int i = 0; i < 16; i++) {
            cs += redS[t + i];
            cm = fmaxf(cm, redM[t + i]);
        }
        cellsum[bc * 16 + cell] = cs;
        cellmax[bc * 16 + cell] = cm;
    }
}

// ---------------- KB: channel attention -> ca ----------------
__global__ void kb_attn(const float* __restrict__ cellsum, const float* __restrict__ cellmax,
                        const float* __restrict__ mw1, const float* __restrict__ mw2,
                        const float* __restrict__ lw1, const float* __restrict__ lw2,
                        const float* __restrict__ fw, float* __restrict__ ca) {
    __shared__ float avgS[256], maxS[256], locS[256 * 16], hid[32], hlS[256];
    int b = blockIdx.x, t = threadIdx.x;
    float s = 0.f, m = -3.4e38f;
#pragma unroll
    for (int cell = 0; cell < 16; cell++) {
        float cs = cellsum[(b * 256 + t) * 16 + cell];
        float cm = cellmax[(b * 256 + t) * 16 + cell];
        s += cs;
        m = fmaxf(m, cm);
        locS[t * 16 + cell] = cs * (1.f / 1600.f);
    }
    avgS[t] = s * (1.f / 25600.f);
    maxS[t] = m;
    __syncthreads();
    if (t < 32) {
        int j = t & 15;
        const float* w1 = mw1 + j * 256;
        const float* src = (t < 16) ? avgS : maxS;
        float h = 0.f;
        for (int c = 0; c < 256; c++) h += w1[c] * src[c];
        hid[t] = fmaxf(h, 0.f);
    }
    {
        int cell = t >> 4, j = t & 15;
        const float* w1 = lw1 + j * 256;
        float h = 0.f;
        for (int c = 0; c < 256; c++) h += w1[c] * locS[c * 16 + cell];
        hlS[t] = fmaxf(h, 0.f);       // hlS[cell*16 + j]
    }
    __syncthreads();
    float ga = 0.f, gm = 0.f;
#pragma unroll
    for (int j = 0; j < 16; j++) {
        float w2 = mw2[t * 16 + j];
        ga += w2 * hid[j];
        gm += w2 * hid[16 + j];
    }
    float la = 0.f;
#pragma unroll
    for (int cell = 0; cell < 16; cell++)
#pragma unroll
        for (int j = 0; j < 16; j++)
            la += lw2[t * 16 + j] * hlS[cell * 16 + j];
    float alpha = 1.f / (1.f + expf(-fw[0]));
    float pre = alpha * (ga + gm) + (1.f - alpha) * (la * (1.f / 16.f));
    ca[b * 256 + t] = 1.f / (1.f + expf(-pre));
}

// ---------------- K3: sf = channel avg/max of ca*x ----------------
__global__ void k3_sf(const float* __restrict__ xal,
                      const float* __restrict__ ca, float* __restrict__ sf) {
    __shared__ float cas[256];
    int b = blockIdx.y, t = threadIdx.x;
    cas[t] = ca[b * 256 + t];
    __syncthreads();
    int p = blockIdx.x * 256 + t;      // one pixel per thread
    const float* base = xal + (size_t)b * NC * HW + p;
    float s0 = 0.f, m0 = -3.4e38f;
    for (int c = 0; c < 256; c++) {
        float a0 = cas[c] * base[(size_t)c * HW];
        s0 += a0;
        m0 = fmaxf(m0, a0);
    }
    sf[(size_t)b * 2 * HW + p]      = s0 * (1.f / 256.f);
    sf[(size_t)b * 2 * HW + HW + p] = m0;
}

// ---------------- K4: offset conv1 3x3 + inline BN + ReLU ----------------
__global__ void k4_conv1(const float* __restrict__ sf, const float* __restrict__ ow1,
                         const float* __restrict__ og, const float* __restrict__ obt,
                         const float* __restrict__ om, const float* __restrict__ ov,
                         float* __restrict__ o1) {
    __shared__ float wS[288], scS[16], shS[16];
    int b = blockIdx.y, t = threadIdx.x;
    for (int i = t; i < 288; i += 256) wS[i] = ow1[i];
    if (t < 16) {
        float sc = og[t] * rsqrtf(ov[t] + 1e-5f);
        scS[t] = sc;
        shS[t] = obt[t] - om[t] * sc;
    }
    __syncthreads();
    int p = blockIdx.x * 256 + t;
    int h = p / 160, w = p - h * 160;
    const float* a0 = sf + (size_t)b * 2 * HW;
    const float* a1 = a0 + HW;
    float in0[9], in1[9];
#pragma unroll
    for (int kh = 0; kh < 3; kh++)
#pragma unroll
        for (int kw = 0; kw < 3; kw++) {
            int hh = h + kh - 1, ww = w + kw - 1;
            bool ok = (hh >= 0) & (hh < 160) & (ww >= 0) & (ww < 160);
            int q = hh * 160 + ww;
            in0[kh * 3 + kw] = ok ? a0[q] : 0.f;
            in1[kh * 3 + kw] = ok ? a1[q] : 0.f;
        }
    float* outb = o1 + (size_t)b * 16 * HW + p;
#pragma unroll
    for (int j = 0; j < 16; j++) {
        float acc = 0.f;
#pragma unroll
        for (int k = 0; k < 9; k++)
            acc += wS[j * 18 + k] * in0[k] + wS[j * 18 + 9 + k] * in1[k];
        outb[(size_t)j * HW] = fmaxf(acc * scS[j] + shS[j], 0.f);
    }
}

// ---------------- K5: folded conv2 (2 ch) -> tanh -> grid_sample ----------------
__global__ void k5_sample(const float* __restrict__ o1, const float* __restrict__ weff,
                          const float* __restrict__ beff, const float* __restrict__ sf,
                          float* __restrict__ sampled) {
    __shared__ float tileS[16 * 18 * 18];
    __shared__ float wS[288];
    __shared__ float bS[2];
    int b = blockIdx.y, t = threadIdx.x;
    int ty0 = (blockIdx.x / 10) * 16, tx0 = (blockIdx.x % 10) * 16;
    const float* ob = o1 + (size_t)b * 16 * HW;
    for (int i = t; i < 288; i += 256) wS[i] = weff[i];
    if (t < 2) bS[t] = beff[t];
    for (int i = t; i < 16 * 18 * 18; i += 256) {
        int ci = i / 324, rem = i - ci * 324;
        int r = rem / 18, c = rem - r * 18;
        int gr = ty0 + r - 1, gc = tx0 + c - 1;
        bool ok = (gr >= 0) & (gr < 160) & (gc >= 0) & (gc < 160);
        tileS[i] = ok ? ob[(size_t)ci * HW + gr * 160 + gc] : 0.f;
    }
    __syncthreads();
    int ty = t >> 4, tx = t & 15;
    int h = ty0 + ty, w = tx0 + tx;
    int p = h * 160 + w;
    float s0 = bS[0], s1 = bS[1];
#pragma unroll
    for (int ci = 0; ci < 16; ci++) {
        const float* tb = &tileS[ci * 324 + ty * 18 + tx];
        const float* w0 = &wS[ci * 9];
        const float* w1 = &wS[144 + ci * 9];
#pragma unroll
        for (int kh = 0; kh < 3; kh++)
#pragma unroll
            for (int kw = 0; kw < 3; kw++) {
                float v = tb[kh * 18 + kw];
                s0 += w0[kh * 3 + kw] * v;
                s1 += w1[kh * 3 + kw] * v;
            }
    }
    float ox = tanhf(s0) * 0.5f;
    float oy = tanhf(s1) * 0.5f;
    float bx = w * (2.f / 159.f) - 1.f, by = h * (2.f / 159.f) - 1.f;
    float gxn = fminf(fmaxf(bx + ox, -1.f), 1.f);
    float gyn = fminf(fmaxf(by + oy, -1.f), 1.f);
    float gx = (gxn + 1.f) * 80.f - 0.5f;
    float gy = (gyn + 1.f) * 80.f - 0.5f;
    float x0f = floorf(gx), y0f = floorf(gy);
    float wx = gx - x0f, wy = gy - y0f;
    int ix0 = (int)x0f, iy0 = (int)y0f;
    const float* f0 = sf + (size_t)b * 2 * HW;
    const float* f1 = f0 + HW;
    float r0 = 0.f, r1 = 0.f;
#pragma unroll
    for (int dy = 0; dy < 2; dy++)
#pragma unroll
        for (int dx = 0; dx < 2; dx++) {
            int xi = ix0 + dx, yi = iy0 + dy;
            float wgt = (dx ? wx : 1.f - wx) * (dy ? wy : 1.f - wy);
            if ((xi >= 0) & (xi < 160) & (yi >= 0) & (yi < 160)) {
                int q = yi * 160 + xi;
                r0 += wgt * f0[q];
                r1 += wgt * f1[q];
            }
        }
    float* sb = sampled + (size_t)b * 2 * HW + p;
    sb[0] = r0;
    sb[HW] = r1;
}

// ---------------- K5b: 7x7 attn conv + sigmoid -> sa ----------------
__global__ void k5b_sa(const float* __restrict__ sampled, const float* __restrict__ attn_w,
                       float* __restrict__ sa) {
    __shared__ float wS[98];
    int b = blockIdx.y, t = threadIdx.x;
    if (t < 98) wS[t] = attn_w[t];
    __syncthreads();
    int p = blockIdx.x * 256 + t;
    int h = p / 160, w = p - h * 160;
    const float* s0 = sampled + (size_t)b * 2 * HW;
    const float* s1 = s0 + HW;
    float acc = 0.f;
#pragma unroll
    for (int kh = 0; kh < 7; kh++) {
        int hh = h + kh - 3;
        if (hh < 0 || hh >= 160) continue;
#pragma unroll
        for (int kw = 0; kw < 7; kw++) {
            int ww = w + kw - 3;
            if (ww < 0 || ww >= 160) continue;
            int q = hh * 160 + ww;
            acc += wS[kh * 7 + kw] * s0[q] + wS[49 + kh * 7 + kw] * s1[q];
        }
    }
    sa[(size_t)b * HW + p] = 1.f / (1.f + expf(-acc));
}

// ---------------- K6: out = sa * ca * x_al (in place, float4) ----------------
__global__ void k6_out(float* __restrict__ out, const float* __restrict__ ca,
                       const float* __restrict__ sa) {
    unsigned e4 = blockIdx.x * 256 + threadIdx.x;
    unsigned e = e4 * 4;
    unsigned b = e / (256u * HW);
    unsigned rem = e - b * (256u * HW);
    unsigned c = rem / HW;
    unsigned p = rem - c * HW;          // p % 4 == 0 (HW divisible by 4)
    f32x4 v = *(f32x4*)(out + e);
    f32x4 s = *(const f32x4*)(sa + (size_t)b * HW + p);
    float cav = ca[b * 256 + c];
#pragma unroll
    for (int i = 0; i < 4; i++) v[i] = cav * s[i] * v[i];
    *(f32x4*)(out + e) = v;
}

extern "C" void kernel_launch(void* const* d_in, const int* in_sizes, int n_in,
                              void* d_out, int out_size, void* d_ws, size_t ws_size,
                              hipStream_t stream) {
    const float* x       = (const float*)d_in[0];
    const float* align_w = (const float*)d_in[1];
    const float* align_g = (const float*)d_in[2];
    const float* align_b = (const float*)d_in[3];
    const float* align_m = (const float*)d_in[4];
    const float* align_v = (const float*)d_in[5];
    const float* mlp_w1  = (const float*)d_in[6];
    const float* mlp_w2  = (const float*)d_in[7];
    const float* loc_w1  = (const float*)d_in[8];
    const float* loc_w2  = (const float*)d_in[9];
    const float* fusion  = (const float*)d_in[10];
    const float* off_w1  = (const float*)d_in[11];
    const float* off_g   = (const float*)d_in[12];
    const float* off_bt  = (const float*)d_in[13];
    const float* off_m   = (const float*)d_in[14];
    const float* off_v   = (const float*)d_in[15];
    const float* off_w2  = (const float*)d_in[16];
    const float* off_b2  = (const float*)d_in[17];
    const float* attn_w  = (const float*)d_in[18];
    float* out = (float*)d_out;

    char* wsb = (char*)d_ws;
    size_t off = 0;
    auto alloc = [&](size_t bytes) -> void* {
        off = (off + 255) & ~(size_t)255;
        void* p = wsb + off;
        off += bytes;
        return p;
    };
    float* xal = out;   // x_aligned fp32 lives in d_out until K6 rescales in place
    unsigned short* wph = (unsigned short*)alloc(81920 * 2);   // padded per-kk image, hi
    unsigned short* wpl = (unsigned short*)alloc(81920 * 2);   // padded per-kk image, lo
    float* biasp   = (float*)alloc(256 * 4);
    float* cellsum = (float*)alloc(32768 * 4);
    float* cellmax = (float*)alloc(32768 * 4);
    float* ca      = (float*)alloc(2048 * 4);
    float* sf      = (float*)alloc((size_t)NB * 2 * HW * 4);
    float* o1      = (float*)alloc((size_t)NB * 16 * HW * 4);
    float* sampled = (float*)alloc((size_t)NB * 2 * HW * 4);
    float* sa      = (float*)alloc((size_t)NB * HW * 4);
    float* weff    = (float*)alloc(288 * 4);
    float* beff    = (float*)alloc(2 * 4);
    (void)ws_size; (void)in_sizes; (void)n_in; (void)out_size;

    k0_fold<<<dim3(256), 256, 0, stream>>>(align_w, align_g, align_b, align_m, align_v,
                                           wph, wpl, biasp);
    k0b_fold2<<<dim3(1), 320, 0, stream>>>(off_w2, off_b2, weff, beff);
    k1_gemm<<<dim3(200, 8), 256, 0, stream>>>(x, wph, wpl, biasp, xal);
    ka_stats<<<dim3(2048), 256, 0, stream>>>(xal, cellsum, cellmax);
    kb_attn<<<dim3(8), 256, 0, stream>>>(cellsum, cellmax, mlp_w1, mlp_w2,
                                         loc_w1, loc_w2, fusion, ca);
    k3_sf<<<dim3(100, 8), 256, 0, stream>>>(xal, ca, sf);
    k4_conv1<<<dim3(100, 8), 256, 0, stream>>>(sf, off_w1, off_g, off_bt, off_m, off_v, o1);
    k5_sample<<<dim3(100, 8), 256, 0, stream>>>(o1, weff, beff, sf, sampled);
    k5b_sa<<<dim3(100, 8), 256, 0, stream>>>(sampled, attn_w, sa);
    k6_out<<<dim3(51200), 256, 0, stream>>>(out, ca, sa);
}

// Round 3
// 676.443 us; speedup vs baseline: 1.9671x; 1.9671x over previous
//
#include <hip/hip_runtime.h>
#include <hip/hip_bf16.h>

#define HH 160
#define WW 160
#define HW 25600
#define NC 256
#define NB 8

typedef short short8 __attribute__((ext_vector_type(8)));
typedef float f32x4 __attribute__((ext_vector_type(4)));

__device__ __forceinline__ unsigned short f2bf(float f) {
    unsigned u = __float_as_uint(f);
    u += 0x7fffu + ((u >> 16) & 1u);   // RNE
    return (unsigned short)(u >> 16);
}
__device__ __forceinline__ float bf2f(unsigned short h) {
    return __uint_as_float(((unsigned)h) << 16);
}

// ---------------- K0: fold BN into align 1x1 conv, split hi/lo bf16, pre-pack ----------------
// Writes the padded per-kk LDS image directly: wpkh[kk*10240 + co*40 + kq] (kq = k - 32*kk).
__global__ void k0_fold(const float* __restrict__ aw, const float* __restrict__ ag,
                        const float* __restrict__ ab, const float* __restrict__ am,
                        const float* __restrict__ av,
                        unsigned short* __restrict__ wpkh, unsigned short* __restrict__ wpkl,
                        float* __restrict__ biasp) {
    int co = blockIdx.x, t = threadIdx.x;       // t = k (ci)
    float sc = ag[co] * rsqrtf(av[co] + 1e-5f);
    float w = aw[co * 256 + t] * sc;
    unsigned short h = f2bf(w);
    int kk = t >> 5, kq = t & 31;
    wpkh[kk * 10240 + co * 40 + kq] = h;
    wpkl[kk * 10240 + co * 40 + kq] = f2bf(w - bf2f(h));
    if (t == 0) biasp[co] = ab[co] - am[co] * sc;
}

// ---------------- K0b: fold the 49-way mean of conv2 into effective weights ----------------
__global__ void k0b_fold2(const float* __restrict__ ow2, const float* __restrict__ ob2,
                          float* __restrict__ weff, float* __restrict__ beff) {
    int t = threadIdx.x;
    if (t < 288) {
        int g = t / 144, r = t - g * 144;
        float s = 0.f;
        for (int q = 0; q < 49; q++) s += ow2[(size_t)(g * 49 + q) * 144 + r];
        weff[t] = s * (1.f / 49.f);
    }
    if (t < 2) {
        float s = 0.f;
        for (int q = 0; q < 49; q++) s += ob2[t * 49 + q];
        beff[t] = s * (1.f / 49.f);
    }
}

// ---------------- K1: align GEMM (split-bf16 MFMA, ~fp32) + bias + SiLU ----------------
// BM=256 (4 waves x 64 co), BN=128, BK=32. A staged via global_load_lds from the
// pre-packed padded image; B converted in-register (RNE hi/lo).
// NOTE: nt loop MUST be fully unrolled — partial unroll makes acc[][] runtime-indexed
// and spills the whole accumulator to scratch (R1 post-mortem: 2 GB WRITE_SIZE).
__global__ __launch_bounds__(256, 2) void k1_gemm(
    const float* __restrict__ X, const unsigned short* __restrict__ Wph,
    const unsigned short* __restrict__ Wpl,
    const float* __restrict__ biasp, float* __restrict__ xal) {
    __shared__ __align__(16) unsigned short Ah[10240];   // [co][kq] stride 40 (80 B rows)
    __shared__ __align__(16) unsigned short Al[10240];
    __shared__ __align__(16) unsigned short Bh[5120];    // [n][kq] stride 40, n 0..127
    __shared__ __align__(16) unsigned short Bl[5120];

    int t = threadIdx.x;
    int n0 = blockIdx.x * 128;
    int b  = blockIdx.y;
    const float* Xb = X + (size_t)b * NC * HW;

    int lane = t & 63, wv = t >> 6;
    int lcol = lane & 15, lq = lane >> 4;

    f32x4 acc[4][8];
#pragma unroll
    for (int i = 0; i < 4; i++)
#pragma unroll
        for (int j = 0; j < 8; j++) { f32x4 z = {0.f, 0.f, 0.f, 0.f}; acc[i][j] = z; }

    int bn2 = t & 63;       // pixel-pair index (pixels 2*bn2, 2*bn2+1)
    int bkq = t >> 6;       // base k-quad (== wv)

    for (int kk = 0; kk < 8; kk++) {
        // ---- A: async global->LDS, 20 KB hi + 20 KB lo, linear image copy ----
        const char* gah = (const char*)(Wph + kk * 10240);
        const char* gal = (const char*)(Wpl + kk * 10240);
#pragma unroll
        for (int i = 0; i < 5; i++) {
            int off = wv * 1024 + i * 4096;    // wave-uniform byte offset
            __builtin_amdgcn_global_load_lds(
                (const __attribute__((address_space(1))) unsigned int*)(gah + off + lane * 16),
                (__attribute__((address_space(3))) unsigned int*)((char*)Ah + off),
                16, 0, 0);
            __builtin_amdgcn_global_load_lds(
                (const __attribute__((address_space(1))) unsigned int*)(gal + off + lane * 16),
                (__attribute__((address_space(3))) unsigned int*)((char*)Al + off),
                16, 0, 0);
        }
        // ---- B: load fp32, RNE hi/lo split, stage to LDS ----
#pragma unroll
        for (int j2 = 0; j2 < 2; j2++) {
            int kq = bkq + 4 * j2;             // k-quad 0..7
            const float* src = Xb + (size_t)(kk * 32 + kq * 4) * HW + n0 + bn2 * 2;
            unsigned h0[2], h1[2], l0[2], l1[2];
#pragma unroll
            for (int j = 0; j < 2; j++) {
                float2 v0 = *(const float2*)(src + (size_t)(2 * j) * HW);
                float2 v1 = *(const float2*)(src + (size_t)(2 * j + 1) * HW);
                unsigned short a = f2bf(v0.x), bq = f2bf(v1.x);
                unsigned short c = f2bf(v0.y), d = f2bf(v1.y);
                h0[j] = (unsigned)a | ((unsigned)bq << 16);
                h1[j] = (unsigned)c | ((unsigned)d << 16);
                unsigned short la = f2bf(v0.x - bf2f(a)), lb = f2bf(v1.x - bf2f(bq));
                unsigned short lc = f2bf(v0.y - bf2f(c)), ld = f2bf(v1.y - bf2f(d));
                l0[j] = (unsigned)la | ((unsigned)lb << 16);
                l1[j] = (unsigned)lc | ((unsigned)ld << 16);
            }
            *(uint2*)(&Bh[(bn2 * 2) * 40 + kq * 4])     = make_uint2(h0[0], h0[1]);
            *(uint2*)(&Bh[(bn2 * 2 + 1) * 40 + kq * 4]) = make_uint2(h1[0], h1[1]);
            *(uint2*)(&Bl[(bn2 * 2) * 40 + kq * 4])     = make_uint2(l0[0], l0[1]);
            *(uint2*)(&Bl[(bn2 * 2 + 1) * 40 + kq * 4]) = make_uint2(l1[0], l1[1]);
        }
        __syncthreads();   // drains global_load_lds (vmcnt) + ds_writes

        short8 afh[4], afl[4];
#pragma unroll
        for (int mt = 0; mt < 4; mt++) {
            afh[mt] = *(const short8*)(&Ah[(wv * 64 + mt * 16 + lcol) * 40 + lq * 8]);
            afl[mt] = *(const short8*)(&Al[(wv * 64 + mt * 16 + lcol) * 40 + lq * 8]);
        }
#pragma unroll
        for (int nt = 0; nt < 8; nt++) {
            short8 bh = *(const short8*)(&Bh[(nt * 16 + lcol) * 40 + lq * 8]);
            short8 bl = *(const short8*)(&Bl[(nt * 16 + lcol) * 40 + lq * 8]);
#pragma unroll
            for (int mt = 0; mt < 4; mt++) {
                acc[mt][nt] = __builtin_amdgcn_mfma_f32_16x16x32_bf16(
                    afh[mt], bh, acc[mt][nt], 0, 0, 0);
                acc[mt][nt] = __builtin_amdgcn_mfma_f32_16x16x32_bf16(
                    afh[mt], bl, acc[mt][nt], 0, 0, 0);
                acc[mt][nt] = __builtin_amdgcn_mfma_f32_16x16x32_bf16(
                    afl[mt], bh, acc[mt][nt], 0, 0, 0);
            }
        }
        __syncthreads();
    }
#pragma unroll
    for (int mt = 0; mt < 4; mt++) {
#pragma unroll
        for (int r = 0; r < 4; r++) {
            int co = wv * 64 + mt * 16 + lq * 4 + r;
            float bias = biasp[co];
            size_t rowbase = ((size_t)b * NC + co) * HW + n0;
#pragma unroll
            for (int nt = 0; nt < 8; nt++) {
                int n = nt * 16 + lcol;
                float y = acc[mt][nt][r] + bias;
                float z = y / (1.f + __expf(-y));   // SiLU
                xal[rowbase + n] = z;
            }
        }
    }
}

// ---------------- KA: per-(b,c) stats: 16 cell sums + cell maxes ----------------
__global__ void ka_stats(const float* __restrict__ xal,
                         float* __restrict__ cellsum, float* __restrict__ cellmax) {
    __shared__ float redS[256], redM[256];
    int bc = blockIdx.x;
    int t = threadIdx.x;
    int cell = t >> 4, s = t & 15;
    int ch = cell >> 2, cw = cell & 3;
    const float* base = xal + (size_t)bc * HW;
    float sm = 0.f, mx = -3.4e38f;
    for (int k = 0; k < 100; k++) {
        int idx = s + 16 * k;            // 0..1599 within cell
        int r = idx / 40, col = idx - r * 40;
        float v = base[(ch * 40 + r) * 160 + cw * 40 + col];
        sm += v;
        mx = fmaxf(mx, v);
    }
    redS[t] = sm;
    redM[t] = mx;
    __syncthreads();
    if (s == 0) {
        float cs = 0.f, cm = -3.4e38f;
#pragma unroll
        for (int i = 0; i < 16; i++) {
            cs += redS[t + i];
            cm = fmaxf(cm, redM[t + i]);
        }
        cellsum[bc * 16 + cell] = cs;
        cellmax[bc * 16 + cell] = cm;
    }
}

// ---------------- KB: channel attention -> ca ----------------
__global__ void kb_attn(const float* __restrict__ cellsum, const float* __restrict__ cellmax,
                        const float* __restrict__ mw1, const float* __restrict__ mw2,
                        const float* __restrict__ lw1, const float* __restrict__ lw2,
                        const float* __restrict__ fw, float* __restrict__ ca) {
    __shared__ float avgS[256], maxS[256], locS[256 * 16], hid[32], hlS[256];
    int b = blockIdx.x, t = threadIdx.x;
    float s = 0.f, m = -3.4e38f;
#pragma unroll
    for (int cell = 0; cell < 16; cell++) {
        float cs = cellsum[(b * 256 + t) * 16 + cell];
        float cm = cellmax[(b * 256 + t) * 16 + cell];
        s += cs;
        m = fmaxf(m, cm);
        locS[t * 16 + cell] = cs * (1.f / 1600.f);
    }
    avgS[t] = s * (1.f / 25600.f);
    maxS[t] = m;
    __syncthreads();
    if (t < 32) {
        int j = t & 15;
        const float* w1 = mw1 + j * 256;
        const float* src = (t < 16) ? avgS : maxS;
        float h = 0.f;
        for (int c = 0; c < 256; c++) h += w1[c] * src[c];
        hid[t] = fmaxf(h, 0.f);
    }
    {
        int cell = t >> 4, j = t & 15;
        const float* w1 = lw1 + j * 256;
        float h = 0.f;
        for (int c = 0; c < 256; c++) h += w1[c] * locS[c * 16 + cell];
        hlS[t] = fmaxf(h, 0.f);       // hlS[cell*16 + j]
    }
    __syncthreads();
    float ga = 0.f, gm = 0.f;
#pragma unroll
    for (int j = 0; j < 16; j++) {
        float w2 = mw2[t * 16 + j];
        ga += w2 * hid[j];
        gm += w2 * hid[16 + j];
    }
    float la = 0.f;
#pragma unroll
    for (int cell = 0; cell < 16; cell++)
#pragma unroll
        for (int j = 0; j < 16; j++)
            la += lw2[t * 16 + j] * hlS[cell * 16 + j];
    float alpha = 1.f / (1.f + expf(-fw[0]));
    float pre = alpha * (ga + gm) + (1.f - alpha) * (la * (1.f / 16.f));
    ca[b * 256 + t] = 1.f / (1.f + expf(-pre));
}

// ---------------- K3: sf = channel avg/max of ca*x ----------------
__global__ void k3_sf(const float* __restrict__ xal,
                      const float* __restrict__ ca, float* __restrict__ sf) {
    __shared__ float cas[256];
    int b = blockIdx.y, t = threadIdx.x;
    cas[t] = ca[b * 256 + t];
    __syncthreads();
    int p = blockIdx.x * 256 + t;      // one pixel per thread
    const float* base = xal + (size_t)b * NC * HW + p;
    float s0 = 0.f, m0 = -3.4e38f;
    for (int c = 0; c < 256; c++) {
        float a0 = cas[c] * base[(size_t)c * HW];
        s0 += a0;
        m0 = fmaxf(m0, a0);
    }
    sf[(size_t)b * 2 * HW + p]      = s0 * (1.f / 256.f);
    sf[(size_t)b * 2 * HW + HW + p] = m0;
}

// ---------------- K4: offset conv1 3x3 + inline BN + ReLU ----------------
__global__ void k4_conv1(const float* __restrict__ sf, const float* __restrict__ ow1,
                         const float* __restrict__ og, const float* __restrict__ obt,
                         const float* __restrict__ om, const float* __restrict__ ov,
                         float* __restrict__ o1) {
    __shared__ float wS[288], scS[16], shS[16];
    int b = blockIdx.y, t = threadIdx.x;
    for (int i = t; i < 288; i += 256) wS[i] = ow1[i];
    if (t < 16) {
        float sc = og[t] * rsqrtf(ov[t] + 1e-5f);
        scS[t] = sc;
        shS[t] = obt[t] - om[t] * sc;
    }
    __syncthreads();
    int p = blockIdx.x * 256 + t;
    int h = p / 160, w = p - h * 160;
    const float* a0 = sf + (size_t)b * 2 * HW;
    const float* a1 = a0 + HW;
    float in0[9], in1[9];
#pragma unroll
    for (int kh = 0; kh < 3; kh++)
#pragma unroll
        for (int kw = 0; kw < 3; kw++) {
            int hh = h + kh - 1, ww = w + kw - 1;
            bool ok = (hh >= 0) & (hh < 160) & (ww >= 0) & (ww < 160);
            int q = hh * 160 + ww;
            in0[kh * 3 + kw] = ok ? a0[q] : 0.f;
            in1[kh * 3 + kw] = ok ? a1[q] : 0.f;
        }
    float* outb = o1 + (size_t)b * 16 * HW + p;
#pragma unroll
    for (int j = 0; j < 16; j++) {
        float acc = 0.f;
#pragma unroll
        for (int k = 0; k < 9; k++)
            acc += wS[j * 18 + k] * in0[k] + wS[j * 18 + 9 + k] * in1[k];
        outb[(size_t)j * HW] = fmaxf(acc * scS[j] + shS[j], 0.f);
    }
}

// ---------------- K5: folded conv2 (2 ch) -> tanh -> grid_sample ----------------
__global__ void k5_sample(const float* __restrict__ o1, const float* __restrict__ weff,
                          const float* __restrict__ beff, const float* __restrict__ sf,
                          float* __restrict__ sampled) {
    __shared__ float tileS[16 * 18 * 18];
    __shared__ float wS[288];
    __shared__ float bS[2];
    int b = blockIdx.y, t = threadIdx.x;
    int ty0 = (blockIdx.x / 10) * 16, tx0 = (blockIdx.x % 10) * 16;
    const float* ob = o1 + (size_t)b * 16 * HW;
    for (int i = t; i < 288; i += 256) wS[i] = weff[i];
    if (t < 2) bS[t] = beff[t];
    for (int i = t; i < 16 * 18 * 18; i += 256) {
        int ci = i / 324, rem = i - ci * 324;
        int r = rem / 18, c = rem - r * 18;
        int gr = ty0 + r - 1, gc = tx0 + c - 1;
        bool ok = (gr >= 0) & (gr < 160) & (gc >= 0) & (gc < 160);
        tileS[i] = ok ? ob[(size_t)ci * HW + gr * 160 + gc] : 0.f;
    }
    __syncthreads();
    int ty = t >> 4, tx = t & 15;
    int h = ty0 + ty, w = tx0 + tx;
    int p = h * 160 + w;
    float s0 = bS[0], s1 = bS[1];
#pragma unroll
    for (int ci = 0; ci < 16; ci++) {
        const float* tb = &tileS[ci * 324 + ty * 18 + tx];
        const float* w0 = &wS[ci * 9];
        const float* w1 = &wS[144 + ci * 9];
#pragma unroll
        for (int kh = 0; kh < 3; kh++)
#pragma unroll
            for (int kw = 0; kw < 3; kw++) {
                float v = tb[kh * 18 + kw];
                s0 += w0[kh * 3 + kw] * v;
                s1 += w1[kh * 3 + kw] * v;
            }
    }
    float ox = tanhf(s0) * 0.5f;
    float oy = tanhf(s1) * 0.5f;
    float bx = w * (2.f / 159.f) - 1.f, by = h * (2.f / 159.f) - 1.f;
    float gxn = fminf(fmaxf(bx + ox, -1.f), 1.f);
    float gyn = fminf(fmaxf(by + oy, -1.f), 1.f);
    float gx = (gxn + 1.f) * 80.f - 0.5f;
    float gy = (gyn + 1.f) * 80.f - 0.5f;
    float x0f = floorf(gx), y0f = floorf(gy);
    float wx = gx - x0f, wy = gy - y0f;
    int ix0 = (int)x0f, iy0 = (int)y0f;
    const float* f0 = sf + (size_t)b * 2 * HW;
    const float* f1 = f0 + HW;
    float r0 = 0.f, r1 = 0.f;
#pragma unroll
    for (int dy = 0; dy < 2; dy++)
#pragma unroll
        for (int dx = 0; dx < 2; dx++) {
            int xi = ix0 + dx, yi = iy0 + dy;
            float wgt = (dx ? wx : 1.f - wx) * (dy ? wy : 1.f - wy);
            if ((xi >= 0) & (xi < 160) & (yi >= 0) & (yi < 160)) {
                int q = yi * 160 + xi;
                r0 += wgt * f0[q];
                r1 += wgt * f1[q];
            }
        }
    float* sb = sampled + (size_t)b * 2 * HW + p;
    sb[0] = r0;
    sb[HW] = r1;
}

// ---------------- K5b: 7x7 attn conv + sigmoid -> sa ----------------
__global__ void k5b_sa(const float* __restrict__ sampled, const float* __restrict__ attn_w,
                       float* __restrict__ sa) {
    __shared__ float wS[98];
    int b = blockIdx.y, t = threadIdx.x;
    if (t < 98) wS[t] = attn_w[t];
    __syncthreads();
    int p = blockIdx.x * 256 + t;
    int h = p / 160, w = p - h * 160;
    const float* s0 = sampled + (size_t)b * 2 * HW;
    const float* s1 = s0 + HW;
    float acc = 0.f;
#pragma unroll
    for (int kh = 0; kh < 7; kh++) {
        int hh = h + kh - 3;
        if (hh < 0 || hh >= 160) continue;
#pragma unroll
        for (int kw = 0; kw < 7; kw++) {
            int ww = w + kw - 3;
            if (ww < 0 || ww >= 160) continue;
            int q = hh * 160 + ww;
            acc += wS[kh * 7 + kw] * s0[q] + wS[49 + kh * 7 + kw] * s1[q];
        }
    }
    sa[(size_t)b * HW + p] = 1.f / (1.f + expf(-acc));
}

// ---------------- K6: out = sa * ca * x_al (in place, float4) ----------------
__global__ void k6_out(float* __restrict__ out, const float* __restrict__ ca,
                       const float* __restrict__ sa) {
    unsigned e4 = blockIdx.x * 256 + threadIdx.x;
    unsigned e = e4 * 4;
    unsigned b = e / (256u * HW);
    unsigned rem = e - b * (256u * HW);
    unsigned c = rem / HW;
    unsigned p = rem - c * HW;          // p % 4 == 0 (HW divisible by 4)
    f32x4 v = *(f32x4*)(out + e);
    f32x4 s = *(const f32x4*)(sa + (size_t)b * HW + p);
    float cav = ca[b * 256 + c];
#pragma unroll
    for (int i = 0; i < 4; i++) v[i] = cav * s[i] * v[i];
    *(f32x4*)(out + e) = v;
}

extern "C" void kernel_launch(void* const* d_in, const int* in_sizes, int n_in,
                              void* d_out, int out_size, void* d_ws, size_t ws_size,
                              hipStream_t stream) {
    const float* x       = (const float*)d_in[0];
    const float* align_w = (const float*)d_in[1];
    const float* align_g = (const float*)d_in[2];
    const float* align_b = (const float*)d_in[3];
    const float* align_m = (const float*)d_in[4];
    const float* align_v = (const float*)d_in[5];
    const float* mlp_w1  = (const float*)d_in[6];
    const float* mlp_w2  = (const float*)d_in[7];
    const float* loc_w1  = (const float*)d_in[8];
    const float* loc_w2  = (const float*)d_in[9];
    const float* fusion  = (const float*)d_in[10];
    const float* off_w1  = (const float*)d_in[11];
    const float* off_g   = (const float*)d_in[12];
    const float* off_bt  = (const float*)d_in[13];
    const float* off_m   = (const float*)d_in[14];
    const float* off_v   = (const float*)d_in[15];
    const float* off_w2  = (const float*)d_in[16];
    const float* off_b2  = (const float*)d_in[17];
    const float* attn_w  = (const float*)d_in[18];
    float* out = (float*)d_out;

    char* wsb = (char*)d_ws;
    size_t off = 0;
    auto alloc = [&](size_t bytes) -> void* {
        off = (off + 255) & ~(size_t)255;
        void* p = wsb + off;
        off += bytes;
        return p;
    };
    float* xal = out;   // x_aligned fp32 lives in d_out until K6 rescales in place
    unsigned short* wph = (unsigned short*)alloc(81920 * 2);   // padded per-kk image, hi
    unsigned short* wpl = (unsigned short*)alloc(81920 * 2);   // padded per-kk image, lo
    float* biasp   = (float*)alloc(256 * 4);
    float* cellsum = (float*)alloc(32768 * 4);
    float* cellmax = (float*)alloc(32768 * 4);
    float* ca      = (float*)alloc(2048 * 4);
    float* sf      = (float*)alloc((size_t)NB * 2 * HW * 4);
    float* o1      = (float*)alloc((size_t)NB * 16 * HW * 4);
    float* sampled = (float*)alloc((size_t)NB * 2 * HW * 4);
    float* sa      = (float*)alloc((size_t)NB * HW * 4);
    float* weff    = (float*)alloc(288 * 4);
    float* beff    = (float*)alloc(2 * 4);
    (void)ws_size; (void)in_sizes; (void)n_in; (void)out_size;

    k0_fold<<<dim3(256), 256, 0, stream>>>(align_w, align_g, align_b, align_m, align_v,
                                           wph, wpl, biasp);
    k0b_fold2<<<dim3(1), 320, 0, stream>>>(off_w2, off_b2, weff, beff);
    k1_gemm<<<dim3(200, 8), 256, 0, stream>>>(x, wph, wpl, biasp, xal);
    ka_stats<<<dim3(2048), 256, 0, stream>>>(xal, cellsum, cellmax);
    kb_attn<<<dim3(8), 256, 0, stream>>>(cellsum, cellmax, mlp_w1, mlp_w2,
                                         loc_w1, loc_w2, fusion, ca);
    k3_sf<<<dim3(100, 8), 256, 0, stream>>>(xal, ca, sf);
    k4_conv1<<<dim3(100, 8), 256, 0, stream>>>(sf, off_w1, off_g, off_bt, off_m, off_v, o1);
    k5_sample<<<dim3(100, 8), 256, 0, stream>>>(o1, weff, beff, sf, sampled);
    k5b_sa<<<dim3(100, 8), 256, 0, stream>>>(sampled, attn_w, sa);
    k6_out<<<dim3(51200), 256, 0, stream>>>(out, ca, sa);
}